// Round 1
// 716.197 us; speedup vs baseline: 2.2387x; 2.2387x over previous
//
#include <hip/hip_runtime.h>
#include <stdint.h>

typedef unsigned short u16;
typedef __attribute__((ext_vector_type(8))) short short8;
typedef __attribute__((ext_vector_type(4))) short short4v;
typedef __attribute__((ext_vector_type(4))) float f32x4;
typedef __attribute__((ext_vector_type(4))) unsigned int u32x4;

__device__ __forceinline__ u16 f2bf(float f) {
  union { float f; uint32_t i; } v; v.f = f;
  uint32_t x = v.i;
  return (u16)((x + 0x7fffu + ((x >> 16) & 1u)) >> 16);  // RNE
}
__device__ __forceinline__ float bf2f(u16 u) {
  union { uint32_t i; float f; } v; v.i = ((uint32_t)u) << 16; return v.f;
}
__device__ __forceinline__ unsigned int packbf(float lo, float hi) {
  return (unsigned int)f2bf(lo) | ((unsigned int)f2bf(hi) << 16);
}

// fp32 -> bf16 convert (weights)
__global__ __launch_bounds__(256) void cvt_kernel(const float* __restrict__ src,
                                                  u16* __restrict__ dst, int n) {
  int i = blockIdx.x * 256 + threadIdx.x;
  if (i < n) dst[i] = f2bf(src[i]);
}

// stable top-8-smallest insert (strict < keeps earlier index on ties, matching top_k)
__device__ __forceinline__ void top8_insert(float (&td)[8], int (&ti)[8], float d, int idx) {
  if (d < td[7]) {
#pragma unroll
    for (int j = 7; j >= 1; --j) {
      bool c1 = d < td[j - 1];
      bool c2 = d < td[j];
      td[j] = c1 ? td[j - 1] : (c2 ? d : td[j]);
      ti[j] = c1 ? ti[j - 1] : (c2 ? idx : ti[j]);
    }
    if (d < td[0]) { td[0] = d; ti[0] = idx; }
  }
}

// merge two sorted 8-lists living in LDS (list i0 holds lower global indices than i1;
// <= keeps i0 on ties -> global stability)
__device__ __forceinline__ void merge2(const float (*sd)[9], const int (*si)[9],
                                       int i0, int i1, float (&md)[8], int (&mi)[8]) {
  int ia = 0, ib = 0;
#pragma unroll
  for (int r = 0; r < 8; ++r) {
    float da = sd[i0][ia], db = sd[i1][ib];
    bool ta = da <= db;
    md[r] = ta ? da : db;
    mi[r] = ta ? si[i0][ia] : si[i1][ib];
    if (ta) ++ia; else ++ib;
  }
}

// ---------------- KNN level2 -> level1 : x1 = concat(l1_cls_feat, interp192) as bf16 ----------------
// 512 threads = 8 waves; wave w scans rows [w*64, w*64+64) of the 512 n2-rows.
__global__ __launch_bounds__(512) void knn_small_kernel(
    const float* __restrict__ l1_to_l2,  // [4,512,2048] fp32
    const float* __restrict__ l2feat,    // [4,512,192]  fp32
    const float* __restrict__ l1feat,    // [4,2048,128] fp32
    u16* __restrict__ x1)                // [4*2048, 320] bf16
{
  const int t = threadIdx.x;
  const int lane = t & 63;
  const int w = t >> 6;                  // 0..7
  const int b = blockIdx.x >> 5;
  const int base = (blockIdx.x & 31) << 6;

  float td[8]; int ti[8];
#pragma unroll
  for (int j = 0; j < 8; ++j) { td[j] = 3.0e38f; ti[j] = 0; }

  const float* dpp = l1_to_l2 + (size_t)b * 512 * 2048 + (size_t)(w * 64) * 2048 + base + lane;
  int idx0 = w * 64;
  for (int it = 0; it < 4; ++it) {       // 4 x 16 = 64 rows per wave
    float dv[16];
#pragma unroll
    for (int u = 0; u < 16; ++u) dv[u] = dpp[(size_t)u * 2048];
    dpp += (size_t)16 * 2048;
#pragma unroll
    for (int u = 0; u < 16; ++u) top8_insert(td, ti, dv[u], idx0 + u);
    idx0 += 16;
  }

  __shared__ float sd[512][9];
  __shared__ int   si[512][9];
  __shared__ float ws[64][8];
  __shared__ int   is_[64][8];
#pragma unroll
  for (int j = 0; j < 8; ++j) { sd[t][j] = td[j]; si[t][j] = ti[j]; }
  __syncthreads();

  float md[8]; int mi[8];
  // stage A: 8 lists -> 4
  if (t < 256) merge2(sd, si, t + ((t >> 6) << 6), t + ((t >> 6) << 6) + 64, md, mi);
  __syncthreads();
  if (t < 256) {
#pragma unroll
    for (int j = 0; j < 8; ++j) { sd[t][j] = md[j]; si[t][j] = mi[j]; }
  }
  __syncthreads();
  // stage B: 4 -> 2
  if (t < 128) merge2(sd, si, t + ((t >> 6) << 6), t + ((t >> 6) << 6) + 64, md, mi);
  __syncthreads();
  if (t < 128) {
#pragma unroll
    for (int j = 0; j < 8; ++j) { sd[t][j] = md[j]; si[t][j] = mi[j]; }
  }
  __syncthreads();
  // stage C: 2 -> 1 + weights
  if (t < 64) {
    merge2(sd, si, t, t + 64, md, mi);
    float wv[8], s = 0.f;
#pragma unroll
    for (int j = 0; j < 8; ++j) { wv[j] = 1.f / (md[j] + 1e-8f); s += wv[j]; }
    const float inv = 1.f / (s + 1e-8f);
#pragma unroll
    for (int j = 0; j < 8; ++j) { ws[t][j] = wv[j] * inv; is_[t][j] = mi[j]; }
  }
  __syncthreads();

  // gather: 8 groups of 64 threads, each handles 8 of the 64 points
  const float* l2b = l2feat + (size_t)b * 512 * 192;
  const int g = t >> 6;                  // == w
  for (int p = 0; p < 8; ++p) {
    const int p2 = (g << 3) + p;
    float a0 = 0.f, a1 = 0.f, a2 = 0.f;
#pragma unroll
    for (int j = 0; j < 8; ++j) {
      const float wj = ws[p2][j];
      const float* frp = l2b + (size_t)is_[p2][j] * 192;
      a0 += wj * frp[lane];
      a1 += wj * frp[lane + 64];
      a2 += wj * frp[lane + 128];
    }
    const int row = b * 2048 + base + p2;
    u16* xr = x1 + (size_t)row * 320;
    const float* lf = l1feat + (size_t)row * 128;
    xr[lane]       = f2bf(lf[lane]);
    xr[64 + lane]  = f2bf(lf[64 + lane]);
    xr[128 + lane] = f2bf(a0);
    xr[192 + lane] = f2bf(a1);
    xr[256 + lane] = f2bf(a2);
  }
}

// ---------------- KNN level1 -> level0 : xcat = concat(radar64, interp640) as bf16 ----------------
// 512 threads = 8 waves; wave w scans rows [w*256, w*256+256) of the 2048 n1-rows.
__global__ __launch_bounds__(512) void knn_big_kernel(
    const float* __restrict__ dist,   // [4,2048,8192] fp32
    const u16* __restrict__ f,        // [4*2048,640] bf16
    const float* __restrict__ radar,  // [4,8192,64] fp32
    u16* __restrict__ xcat)           // [4*8192,704] bf16
{
  const int t = threadIdx.x;
  const int lane = t & 63;
  const int w = t >> 6;                  // 0..7
  const int b = blockIdx.x >> 7;
  const int base = (blockIdx.x & 127) << 6;

  float td[8]; int ti[8];
#pragma unroll
  for (int j = 0; j < 8; ++j) { td[j] = 3.0e38f; ti[j] = 0; }

  const float* dpp = dist + (size_t)b * 2048 * 8192 + (size_t)(w * 256) * 8192 + base + lane;
  int idx0 = w * 256;
  for (int it = 0; it < 16; ++it) {      // 16 x 16 = 256 rows per wave
    float dv[16];
#pragma unroll
    for (int u = 0; u < 16; ++u) dv[u] = dpp[(size_t)u * 8192];
    dpp += (size_t)16 * 8192;
#pragma unroll
    for (int u = 0; u < 16; ++u) top8_insert(td, ti, dv[u], idx0 + u);
    idx0 += 16;
  }

  __shared__ float sd[512][9];
  __shared__ int   si[512][9];
  __shared__ float ws[64][8];
  __shared__ int   is_[64][8];
#pragma unroll
  for (int j = 0; j < 8; ++j) { sd[t][j] = td[j]; si[t][j] = ti[j]; }
  __syncthreads();

  float md[8]; int mi[8];
  // stage A: 8 lists -> 4
  if (t < 256) merge2(sd, si, t + ((t >> 6) << 6), t + ((t >> 6) << 6) + 64, md, mi);
  __syncthreads();
  if (t < 256) {
#pragma unroll
    for (int j = 0; j < 8; ++j) { sd[t][j] = md[j]; si[t][j] = mi[j]; }
  }
  __syncthreads();
  // stage B: 4 -> 2
  if (t < 128) merge2(sd, si, t + ((t >> 6) << 6), t + ((t >> 6) << 6) + 64, md, mi);
  __syncthreads();
  if (t < 128) {
#pragma unroll
    for (int j = 0; j < 8; ++j) { sd[t][j] = md[j]; si[t][j] = mi[j]; }
  }
  __syncthreads();
  // stage C: 2 -> 1 + weights
  if (t < 64) {
    merge2(sd, si, t, t + 64, md, mi);
    float wv[8], s = 0.f;
#pragma unroll
    for (int j = 0; j < 8; ++j) { wv[j] = 1.f / (md[j] + 1e-8f); s += wv[j]; }
    const float inv = 1.f / (s + 1e-8f);
#pragma unroll
    for (int j = 0; j < 8; ++j) { ws[t][j] = wv[j] * inv; is_[t][j] = mi[j]; }
  }
  __syncthreads();

  // gather: 4 groups of 128 threads; each group handles 16 points.
  // f rows (640 bf16 = 320 u32) read as u32 (2 bf16 per load, 256B/wave/instr).
  const u16* fb = f + (size_t)b * 2048 * 640;
  const int g = t >> 7;                  // 0..3
  const int t2 = t & 127;
  const bool lowhalf = (t2 < 64);        // wave-uniform
  for (int p = 0; p < 16; ++p) {
    const int p2 = (g << 4) + p;
    float a0l = 0.f, a0h = 0.f, a1l = 0.f, a1h = 0.f, a2l = 0.f, a2h = 0.f;
#pragma unroll
    for (int j = 0; j < 8; ++j) {
      const float wj = ws[p2][j];
      const unsigned int* fr32 = (const unsigned int*)(fb + (size_t)is_[p2][j] * 640);
      unsigned int v0 = fr32[t2];
      unsigned int v1 = fr32[t2 + 128];
      a0l += wj * bf2f((u16)(v0 & 0xffffu)); a0h += wj * bf2f((u16)(v0 >> 16));
      a1l += wj * bf2f((u16)(v1 & 0xffffu)); a1h += wj * bf2f((u16)(v1 >> 16));
      if (lowhalf) {
        unsigned int v2 = fr32[t2 + 256];
        a2l += wj * bf2f((u16)(v2 & 0xffffu)); a2h += wj * bf2f((u16)(v2 >> 16));
      }
    }
    const int row = (b << 13) + base + p2;
    u16* xr = xcat + (size_t)row * 704;
    if (lowhalf) xr[t2] = f2bf(radar[(size_t)row * 64 + t2]);
    unsigned int* xo = (unsigned int*)(xr + 64);
    xo[t2]       = packbf(a0l, a0h);
    xo[t2 + 128] = packbf(a1l, a1h);
    if (lowhalf) xo[t2 + 256] = packbf(a2l, a2h);
  }
}

// ---------------- fused GEMM + bias + BN(eval) + ReLU ----------------
// C[m,n] = relu(g[m]*inv_sqrt*(sum_k W[m,k]*X[n,k] + b[m]) + be[m])
// W:[M,K] bf16 k-fast, X:[Ntot,K] bf16 k-fast. bias/gamma/beta fp32.
// OUT_MODE 0: bf16 Y[n*M+m]; OUT_MODE 1: fp32 Y[b*M*8192+m*8192+(n%8192)]
#define BM 128
#define BN 128
#define BK 32

template <int OUT_MODE>
__global__ __launch_bounds__(256) void gemm_bf16(
    const u16* __restrict__ W, const u16* __restrict__ X,
    const float* __restrict__ bias, const float* __restrict__ gamma, const float* __restrict__ beta,
    void* __restrict__ Yv, int M, int K, int Ntot)
{
  __shared__ u16 As[BM * BK];
  __shared__ u16 Bs[BN * BK];

  const int t = threadIdx.x;
  const int lane = t & 63;
  const int wv = t >> 6;
  const int mtiles = M >> 7;
  const int mt = (int)blockIdx.x % mtiles;
  const int nt = (int)blockIdx.x / mtiles;
  const int m0 = mt << 7;
  const int n0 = nt << 7;
  const int fr = lane & 15;
  const int quad = lane >> 4;
  const int wr = (wv >> 1) << 6;  // wave m-offset within tile
  const int wc = (wv & 1) << 6;   // wave n-offset within tile

  const f32x4 zero = {0.f, 0.f, 0.f, 0.f};
  f32x4 acc[4][4];
#pragma unroll
  for (int i = 0; i < 4; ++i)
#pragma unroll
    for (int j = 0; j < 4; ++j) acc[i][j] = zero;

  // staging: 512 chunks of 16B per tile; chunk c -> row c/4, k8 (c%4)*8
  const int c0 = (wv << 6) + lane;
  const int c1 = c0 + 256;
  const u16* Wp0 = W + (size_t)(m0 + (c0 >> 2)) * K + ((c0 & 3) << 3);
  const u16* Wp1 = W + (size_t)(m0 + (c1 >> 2)) * K + ((c1 & 3) << 3);
  const u16* Xp0 = X + (size_t)(n0 + (c0 >> 2)) * K + ((c0 & 3) << 3);
  const u16* Xp1 = X + (size_t)(n0 + (c1 >> 2)) * K + ((c1 & 3) << 3);

  for (int k0 = 0; k0 < K; k0 += BK) {
    u32x4 wa = *(const u32x4*)(Wp0 + k0);
    u32x4 wb = *(const u32x4*)(Wp1 + k0);
    u32x4 xa = *(const u32x4*)(Xp0 + k0);
    u32x4 xb = *(const u32x4*)(Xp1 + k0);
    __syncthreads();  // all waves done reading previous tile
    *(u32x4*)(As + (c0 << 3)) = wa;
    *(u32x4*)(As + (c1 << 3)) = wb;
    *(u32x4*)(Bs + (c0 << 3)) = xa;
    *(u32x4*)(Bs + (c1 << 3)) = xb;
    __syncthreads();  // stores visible

    short8 af[4], bfv[4];
#pragma unroll
    for (int i = 0; i < 4; ++i)
      af[i] = *(const short8*)(As + (wr + i * 16 + fr) * BK + (quad << 3));
#pragma unroll
    for (int j = 0; j < 4; ++j)
      bfv[j] = *(const short8*)(Bs + (wc + j * 16 + fr) * BK + (quad << 3));
#pragma unroll
    for (int i = 0; i < 4; ++i)
#pragma unroll
      for (int j = 0; j < 4; ++j)
        acc[i][j] = __builtin_amdgcn_mfma_f32_16x16x32_bf16(af[i], bfv[j], acc[i][j], 0, 0, 0);
  }

  // epilogue: C/D layout col=lane&15 (n), row=quad*4+r (m)
  constexpr float BNS = 0.99999500003749968f;  // 1/sqrt(1+1e-5)
#pragma unroll
  for (int i = 0; i < 4; ++i) {
    const int mb = m0 + wr + i * 16 + (quad << 2);
    float g0[4], b0[4], e0[4];
#pragma unroll
    for (int r = 0; r < 4; ++r) {
      g0[r] = gamma[mb + r] * BNS;
      b0[r] = bias[mb + r];
      e0[r] = beta[mb + r];
    }
#pragma unroll
    for (int j = 0; j < 4; ++j) {
      const int n = n0 + wc + j * 16 + fr;
      if (OUT_MODE == 0) {
        u16* Y = (u16*)Yv;
        short4v sv;
#pragma unroll
        for (int r = 0; r < 4; ++r) {
          float v = g0[r] * (acc[i][j][r] + b0[r]) + e0[r];
          sv[r] = (short)f2bf(fmaxf(v, 0.f));
        }
        *(short4v*)(Y + (size_t)n * M + mb) = sv;
      } else {
        float* Y = (float*)Yv;
        const int bb = n >> 13, nn = n & 8191;
        float* yp = Y + ((size_t)bb * M + mb) * 8192 + nn;
#pragma unroll
        for (int r = 0; r < 4; ++r) {
          float v = g0[r] * (acc[i][j][r] + b0[r]) + e0[r];
          yp[(size_t)r * 8192] = fmaxf(v, 0.f);
        }
      }
    }
  }
}

extern "C" void kernel_launch(void* const* d_in, const int* in_sizes, int n_in,
                              void* d_out, int out_size, void* d_ws, size_t ws_size,
                              hipStream_t stream) {
  (void)in_sizes; (void)n_in; (void)out_size; (void)ws_size;
  const float* radar    = (const float*)d_in[0];   // [4,8192,64]
  const float* l1feat   = (const float*)d_in[1];   // [4,2048,128]
  const float* l2feat   = (const float*)d_in[2];   // [4,512,192]
  const float* l0_to_l1 = (const float*)d_in[3];   // [4,2048,8192]
  const float* l1_to_l2 = (const float*)d_in[4];   // [4,512,2048]
  const float* w21a = (const float*)d_in[5];
  const float* b21a = (const float*)d_in[6];
  const float* g21a = (const float*)d_in[7];
  const float* be21a = (const float*)d_in[8];
  const float* w21b = (const float*)d_in[9];
  const float* b21b = (const float*)d_in[10];
  const float* g21b = (const float*)d_in[11];
  const float* be21b = (const float*)d_in[12];
  const float* w10a = (const float*)d_in[13];
  const float* b10a = (const float*)d_in[14];
  const float* g10a = (const float*)d_in[15];
  const float* be10a = (const float*)d_in[16];
  const float* w10b = (const float*)d_in[17];
  const float* b10b = (const float*)d_in[18];
  const float* g10b = (const float*)d_in[19];
  const float* be10b = (const float*)d_in[20];

  u16* x1   = (u16*)d_ws;                       // [8192,320]
  u16* h1   = x1 + (size_t)8192 * 320;          // [8192,640]
  u16* fbuf = h1 + (size_t)8192 * 640;          // [8192,640]
  u16* xcat = fbuf + (size_t)8192 * 640;        // [32768,704]
  u16* h2   = xcat + (size_t)32768 * 704;       // [32768,640]
  u16* wb21a = h2 + (size_t)32768 * 640;        // [640,320]
  u16* wb21b = wb21a + 640 * 320;               // [640,640]
  u16* wb10a = wb21b + 640 * 640;               // [640,704]
  u16* wb10b = wb10a + 640 * 704;               // [768,640]
  // total ~117 MB of workspace

  cvt_kernel<<<(640 * 320 + 255) / 256, 256, 0, stream>>>(w21a, wb21a, 640 * 320);
  cvt_kernel<<<(640 * 640 + 255) / 256, 256, 0, stream>>>(w21b, wb21b, 640 * 640);
  cvt_kernel<<<(640 * 704 + 255) / 256, 256, 0, stream>>>(w10a, wb10a, 640 * 704);
  cvt_kernel<<<(768 * 640 + 255) / 256, 256, 0, stream>>>(w10b, wb10b, 768 * 640);

  knn_small_kernel<<<128, 512, 0, stream>>>(l1_to_l2, l2feat, l1feat, x1);
  gemm_bf16<0><<<5 * 64, 256, 0, stream>>>(wb21a, x1, b21a, g21a, be21a, h1, 640, 320, 8192);
  gemm_bf16<0><<<5 * 64, 256, 0, stream>>>(wb21b, h1, b21b, g21b, be21b, fbuf, 640, 640, 8192);
  knn_big_kernel<<<512, 512, 0, stream>>>(l0_to_l1, fbuf, radar, xcat);
  gemm_bf16<0><<<5 * 256, 256, 0, stream>>>(wb10a, xcat, b10a, g10a, be10a, h2, 640, 704, 32768);
  gemm_bf16<1><<<6 * 256, 256, 0, stream>>>(wb10b, h2, b10b, g10b, be10b, d_out, 768, 640, 32768);
}

// Round 2
// 688.730 us; speedup vs baseline: 2.3280x; 1.0399x over previous
//
#include <hip/hip_runtime.h>
#include <stdint.h>

typedef unsigned short u16;
typedef __attribute__((ext_vector_type(8))) short short8;
typedef __attribute__((ext_vector_type(4))) short short4v;
typedef __attribute__((ext_vector_type(4))) float f32x4;
typedef __attribute__((ext_vector_type(4))) unsigned int u32x4;

__device__ __forceinline__ u16 f2bf(float f) {
  union { float f; uint32_t i; } v; v.f = f;
  uint32_t x = v.i;
  return (u16)((x + 0x7fffu + ((x >> 16) & 1u)) >> 16);  // RNE
}
__device__ __forceinline__ float bf2f(u16 u) {
  union { uint32_t i; float f; } v; v.i = ((uint32_t)u) << 16; return v.f;
}
__device__ __forceinline__ unsigned int packbf(float lo, float hi) {
  return (unsigned int)f2bf(lo) | ((unsigned int)f2bf(hi) << 16);
}

// async global -> LDS, 16B per lane. lds dest: wave-uniform base + lane*16 (HW adds lane offset).
__device__ __forceinline__ void gl_lds16(const void* g, void* l) {
  __builtin_amdgcn_global_load_lds(
      (const __attribute__((address_space(1))) void*)g,
      (__attribute__((address_space(3))) void*)l, 16, 0, 0);
}

// fp32 -> bf16 convert (weights)
__global__ __launch_bounds__(256) void cvt_kernel(const float* __restrict__ src,
                                                  u16* __restrict__ dst, int n) {
  int i = blockIdx.x * 256 + threadIdx.x;
  if (i < n) dst[i] = f2bf(src[i]);
}

// stable top-8-smallest insert (strict < keeps earlier index on ties, matching top_k)
__device__ __forceinline__ void top8_insert(float (&td)[8], int (&ti)[8], float d, int idx) {
  if (d < td[7]) {
#pragma unroll
    for (int j = 7; j >= 1; --j) {
      bool c1 = d < td[j - 1];
      bool c2 = d < td[j];
      td[j] = c1 ? td[j - 1] : (c2 ? d : td[j]);
      ti[j] = c1 ? ti[j - 1] : (c2 ? idx : ti[j]);
    }
    if (d < td[0]) { td[0] = d; ti[0] = idx; }
  }
}

// merge two sorted 8-lists living in LDS (list i0 holds lower global indices than i1;
// <= keeps i0 on ties -> global stability)
__device__ __forceinline__ void merge2(const float (*sd)[9], const int (*si)[9],
                                       int i0, int i1, float (&md)[8], int (&mi)[8]) {
  int ia = 0, ib = 0;
#pragma unroll
  for (int r = 0; r < 8; ++r) {
    float da = sd[i0][ia], db = sd[i1][ib];
    bool ta = da <= db;
    md[r] = ta ? da : db;
    mi[r] = ta ? si[i0][ia] : si[i1][ib];
    if (ta) ++ia; else ++ib;
  }
}

// ---------------- KNN level2 -> level1 : x1 = concat(l1_cls_feat, interp192) as bf16 ----------------
// 256 blocks: each block = 32 columns (l1 points) of one batch.
// 512 threads = 16 row-segments x 32 columns; segment scans 32 of the 512 n2-rows.
__global__ __launch_bounds__(512) void knn_small_kernel(
    const float* __restrict__ l1_to_l2,  // [4,512,2048] fp32
    const float* __restrict__ l2feat,    // [4,512,192]  fp32
    const float* __restrict__ l1feat,    // [4,2048,128] fp32
    u16* __restrict__ x1)                // [4*2048, 320] bf16
{
  const int t = threadIdx.x;
  const int c = t & 31;                  // column within block
  const int seg = t >> 5;                // 0..15
  const int b = blockIdx.x >> 6;
  const int base = (blockIdx.x & 63) << 5;

  float td[8]; int ti[8];
#pragma unroll
  for (int j = 0; j < 8; ++j) { td[j] = 3.0e38f; ti[j] = 0; }

  const float* dpp = l1_to_l2 + (size_t)b * 512 * 2048 + (size_t)(seg * 32) * 2048 + base + c;
  int idx0 = seg * 32;
  for (int it = 0; it < 2; ++it) {       // 2 x 16 = 32 rows per segment
    float dv[16];
#pragma unroll
    for (int u = 0; u < 16; ++u) dv[u] = dpp[(size_t)u * 2048];
    dpp += (size_t)16 * 2048;
#pragma unroll
    for (int u = 0; u < 16; ++u) top8_insert(td, ti, dv[u], idx0 + u);
    idx0 += 16;
  }

  __shared__ float sd[512][9];
  __shared__ int   si[512][9];
  __shared__ float ws[32][8];
  __shared__ int   is_[32][8];
#pragma unroll
  for (int j = 0; j < 8; ++j) { sd[t][j] = td[j]; si[t][j] = ti[j]; }
  __syncthreads();

  float md[8]; int mi[8];
  // 16 -> 8
  if (t < 256) merge2(sd, si, t + ((t >> 5) << 5), t + ((t >> 5) << 5) + 32, md, mi);
  __syncthreads();
  if (t < 256) {
#pragma unroll
    for (int j = 0; j < 8; ++j) { sd[t][j] = md[j]; si[t][j] = mi[j]; }
  }
  __syncthreads();
  // 8 -> 4
  if (t < 128) merge2(sd, si, t + ((t >> 5) << 5), t + ((t >> 5) << 5) + 32, md, mi);
  __syncthreads();
  if (t < 128) {
#pragma unroll
    for (int j = 0; j < 8; ++j) { sd[t][j] = md[j]; si[t][j] = mi[j]; }
  }
  __syncthreads();
  // 4 -> 2
  if (t < 64) merge2(sd, si, t + ((t >> 5) << 5), t + ((t >> 5) << 5) + 32, md, mi);
  __syncthreads();
  if (t < 64) {
#pragma unroll
    for (int j = 0; j < 8; ++j) { sd[t][j] = md[j]; si[t][j] = mi[j]; }
  }
  __syncthreads();
  // 2 -> 1 + weights
  if (t < 32) {
    merge2(sd, si, t, t + 32, md, mi);
    float wv[8], s = 0.f;
#pragma unroll
    for (int j = 0; j < 8; ++j) { wv[j] = 1.f / (md[j] + 1e-8f); s += wv[j]; }
    const float inv = 1.f / (s + 1e-8f);
#pragma unroll
    for (int j = 0; j < 8; ++j) { ws[t][j] = wv[j] * inv; is_[t][j] = mi[j]; }
  }
  __syncthreads();

  // gather: 8 groups of 64 lanes; each group handles 4 of the 32 points
  const float* l2b = l2feat + (size_t)b * 512 * 192;
  const int g = t >> 6;                  // 0..7
  const int lane = t & 63;
  for (int p = 0; p < 4; ++p) {
    const int p2 = (g << 2) + p;
    float a0 = 0.f, a1 = 0.f, a2 = 0.f;
#pragma unroll
    for (int j = 0; j < 8; ++j) {
      const float wj = ws[p2][j];
      const float* frp = l2b + (size_t)is_[p2][j] * 192;
      a0 += wj * frp[lane];
      a1 += wj * frp[lane + 64];
      a2 += wj * frp[lane + 128];
    }
    const int row = b * 2048 + base + p2;
    u16* xr = x1 + (size_t)row * 320;
    const float* lf = l1feat + (size_t)row * 128;
    xr[lane]       = f2bf(lf[lane]);
    xr[64 + lane]  = f2bf(lf[64 + lane]);
    xr[128 + lane] = f2bf(a0);
    xr[192 + lane] = f2bf(a1);
    xr[256 + lane] = f2bf(a2);
  }
}

// ---------------- KNN level1 -> level0 : xcat = concat(radar64, interp640) as bf16 ----------------
// 1024 threads = 16 waves; wave w scans rows [w*128, w*128+128) of the 2048 n1-rows.
__global__ __launch_bounds__(1024) void knn_big_kernel(
    const float* __restrict__ dist,   // [4,2048,8192] fp32
    const u16* __restrict__ f,        // [4*2048,640] bf16
    const float* __restrict__ radar,  // [4,8192,64] fp32
    u16* __restrict__ xcat)           // [4*8192,704] bf16
{
  const int t = threadIdx.x;
  const int lane = t & 63;
  const int w = t >> 6;                  // 0..15
  const int b = blockIdx.x >> 7;
  const int base = (blockIdx.x & 127) << 6;

  float td[8]; int ti[8];
#pragma unroll
  for (int j = 0; j < 8; ++j) { td[j] = 3.0e38f; ti[j] = 0; }

  const float* dpp = dist + (size_t)b * 2048 * 8192 + (size_t)(w * 128) * 8192 + base + lane;
  int idx0 = w * 128;
  for (int it = 0; it < 8; ++it) {       // 8 x 16 = 128 rows per wave
    float dv[16];
#pragma unroll
    for (int u = 0; u < 16; ++u) dv[u] = dpp[(size_t)u * 8192];
    dpp += (size_t)16 * 8192;
#pragma unroll
    for (int u = 0; u < 16; ++u) top8_insert(td, ti, dv[u], idx0 + u);
    idx0 += 16;
  }

  __shared__ float sd[1024][9];
  __shared__ int   si[1024][9];
  __shared__ float ws[64][8];
  __shared__ int   is_[64][8];
#pragma unroll
  for (int j = 0; j < 8; ++j) { sd[t][j] = td[j]; si[t][j] = ti[j]; }
  __syncthreads();

  float md[8]; int mi[8];
  // 16 -> 8
  if (t < 512) merge2(sd, si, t + ((t >> 6) << 6), t + ((t >> 6) << 6) + 64, md, mi);
  __syncthreads();
  if (t < 512) {
#pragma unroll
    for (int j = 0; j < 8; ++j) { sd[t][j] = md[j]; si[t][j] = mi[j]; }
  }
  __syncthreads();
  // 8 -> 4
  if (t < 256) merge2(sd, si, t + ((t >> 6) << 6), t + ((t >> 6) << 6) + 64, md, mi);
  __syncthreads();
  if (t < 256) {
#pragma unroll
    for (int j = 0; j < 8; ++j) { sd[t][j] = md[j]; si[t][j] = mi[j]; }
  }
  __syncthreads();
  // 4 -> 2
  if (t < 128) merge2(sd, si, t + ((t >> 6) << 6), t + ((t >> 6) << 6) + 64, md, mi);
  __syncthreads();
  if (t < 128) {
#pragma unroll
    for (int j = 0; j < 8; ++j) { sd[t][j] = md[j]; si[t][j] = mi[j]; }
  }
  __syncthreads();
  // 2 -> 1 + weights
  if (t < 64) {
    merge2(sd, si, t, t + 64, md, mi);
    float wv[8], s = 0.f;
#pragma unroll
    for (int j = 0; j < 8; ++j) { wv[j] = 1.f / (md[j] + 1e-8f); s += wv[j]; }
    const float inv = 1.f / (s + 1e-8f);
#pragma unroll
    for (int j = 0; j < 8; ++j) { ws[t][j] = wv[j] * inv; is_[t][j] = mi[j]; }
  }
  __syncthreads();

  // gather: 8 groups of 128 threads; each group handles 8 points.
  // f rows (640 bf16 = 320 u32) read as u32 (2 bf16 per load, 256B/wave/instr).
  const u16* fb = f + (size_t)b * 2048 * 640;
  const int g = t >> 7;                  // 0..7
  const int t2 = t & 127;
  const bool lowhalf = (t2 < 64);        // wave-uniform
  for (int p = 0; p < 8; ++p) {
    const int p2 = (g << 3) + p;
    float a0l = 0.f, a0h = 0.f, a1l = 0.f, a1h = 0.f, a2l = 0.f, a2h = 0.f;
#pragma unroll
    for (int j = 0; j < 8; ++j) {
      const float wj = ws[p2][j];
      const unsigned int* fr32 = (const unsigned int*)(fb + (size_t)is_[p2][j] * 640);
      unsigned int v0 = fr32[t2];
      unsigned int v1 = fr32[t2 + 128];
      a0l += wj * bf2f((u16)(v0 & 0xffffu)); a0h += wj * bf2f((u16)(v0 >> 16));
      a1l += wj * bf2f((u16)(v1 & 0xffffu)); a1h += wj * bf2f((u16)(v1 >> 16));
      if (lowhalf) {
        unsigned int v2 = fr32[t2 + 256];
        a2l += wj * bf2f((u16)(v2 & 0xffffu)); a2h += wj * bf2f((u16)(v2 >> 16));
      }
    }
    const int row = (b << 13) + base + p2;
    u16* xr = xcat + (size_t)row * 704;
    if (lowhalf) xr[t2] = f2bf(radar[(size_t)row * 64 + t2]);
    unsigned int* xo = (unsigned int*)(xr + 64);
    xo[t2]       = packbf(a0l, a0h);
    xo[t2 + 128] = packbf(a1l, a1h);
    if (lowhalf) xo[t2 + 256] = packbf(a2l, a2h);
  }
}

// ---------------- fused GEMM + bias + BN(eval) + ReLU ----------------
// C[m,n] = relu(g[m]*inv_sqrt*(sum_k W[m,k]*X[n,k] + b[m]) + be[m])
// W:[M,K] bf16 k-fast, X:[Ntot,K] bf16 k-fast. bias/gamma/beta fp32.
// OUT_MODE 0: bf16 Y[n*M+m]; OUT_MODE 1: fp32 Y[b*M*8192+m*8192+(n%8192)]
#define BM 128
#define BN 128
#define BK 32

template <int OUT_MODE>
__global__ __launch_bounds__(256) void gemm_bf16(
    const u16* __restrict__ W, const u16* __restrict__ X,
    const float* __restrict__ bias, const float* __restrict__ gamma, const float* __restrict__ beta,
    void* __restrict__ Yv, int M, int K, int Ntot)
{
  __shared__ u16 As[BM * BK];
  __shared__ u16 Bs[BN * BK];

  const int t = threadIdx.x;
  const int lane = t & 63;
  const int wv = t >> 6;
  const int mtiles = M >> 7;
  const int mt = (int)blockIdx.x % mtiles;
  const int nt = (int)blockIdx.x / mtiles;
  const int m0 = mt << 7;
  const int n0 = nt << 7;
  const int fr = lane & 15;
  const int quad = lane >> 4;
  const int wr = (wv >> 1) << 6;  // wave m-offset within tile
  const int wc = (wv & 1) << 6;   // wave n-offset within tile

  const f32x4 zero = {0.f, 0.f, 0.f, 0.f};
  f32x4 acc[4][4];
#pragma unroll
  for (int i = 0; i < 4; ++i)
#pragma unroll
    for (int j = 0; j < 4; ++j) acc[i][j] = zero;

  // staging: 512 chunks of 16B per tile; chunk c -> row c/4, k8 (c%4)*8
  // chunk c0 = wv*64+lane -> LDS byte c0*16 : wave-uniform base + lane*16 (global_load_lds layout)
  const int c0 = (wv << 6) + lane;
  const int c1 = c0 + 256;
  const u16* Wp0 = W + (size_t)(m0 + (c0 >> 2)) * K + ((c0 & 3) << 3);
  const u16* Wp1 = W + (size_t)(m0 + (c1 >> 2)) * K + ((c1 & 3) << 3);
  const u16* Xp0 = X + (size_t)(n0 + (c0 >> 2)) * K + ((c0 & 3) << 3);
  const u16* Xp1 = X + (size_t)(n0 + (c1 >> 2)) * K + ((c1 & 3) << 3);
  char* asB = (char*)As;
  char* bsB = (char*)Bs;

  for (int k0 = 0; k0 < K; k0 += BK) {
    __syncthreads();  // all waves done reading previous tile
    gl_lds16(Wp0 + k0, asB + ((size_t)c0 << 4));
    gl_lds16(Wp1 + k0, asB + ((size_t)c1 << 4));
    gl_lds16(Xp0 + k0, bsB + ((size_t)c0 << 4));
    gl_lds16(Xp1 + k0, bsB + ((size_t)c1 << 4));
    __syncthreads();  // drains vmcnt(0) -> LDS writes visible

    short8 af[4], bfv[4];
#pragma unroll
    for (int i = 0; i < 4; ++i)
      af[i] = *(const short8*)(As + (wr + i * 16 + fr) * BK + (quad << 3));
#pragma unroll
    for (int j = 0; j < 4; ++j)
      bfv[j] = *(const short8*)(Bs + (wc + j * 16 + fr) * BK + (quad << 3));
#pragma unroll
    for (int i = 0; i < 4; ++i)
#pragma unroll
      for (int j = 0; j < 4; ++j)
        acc[i][j] = __builtin_amdgcn_mfma_f32_16x16x32_bf16(af[i], bfv[j], acc[i][j], 0, 0, 0);
  }

  // epilogue: C/D layout col=lane&15 (n), row=quad*4+r (m)
  constexpr float BNS = 0.99999500003749968f;  // 1/sqrt(1+1e-5)
#pragma unroll
  for (int i = 0; i < 4; ++i) {
    const int mb = m0 + wr + i * 16 + (quad << 2);
    float g0[4], b0[4], e0[4];
#pragma unroll
    for (int r = 0; r < 4; ++r) {
      g0[r] = gamma[mb + r] * BNS;
      b0[r] = bias[mb + r];
      e0[r] = beta[mb + r];
    }
#pragma unroll
    for (int j = 0; j < 4; ++j) {
      const int n = n0 + wc + j * 16 + fr;
      if (OUT_MODE == 0) {
        u16* Y = (u16*)Yv;
        short4v sv;
#pragma unroll
        for (int r = 0; r < 4; ++r) {
          float v = g0[r] * (acc[i][j][r] + b0[r]) + e0[r];
          sv[r] = (short)f2bf(fmaxf(v, 0.f));
        }
        *(short4v*)(Y + (size_t)n * M + mb) = sv;
      } else {
        float* Y = (float*)Yv;
        const int bb = n >> 13, nn = n & 8191;
        float* yp = Y + ((size_t)bb * M + mb) * 8192 + nn;
#pragma unroll
        for (int r = 0; r < 4; ++r) {
          float v = g0[r] * (acc[i][j][r] + b0[r]) + e0[r];
          yp[(size_t)r * 8192] = fmaxf(v, 0.f);
        }
      }
    }
  }
}

extern "C" void kernel_launch(void* const* d_in, const int* in_sizes, int n_in,
                              void* d_out, int out_size, void* d_ws, size_t ws_size,
                              hipStream_t stream) {
  (void)in_sizes; (void)n_in; (void)out_size; (void)ws_size;
  const float* radar    = (const float*)d_in[0];   // [4,8192,64]
  const float* l1feat   = (const float*)d_in[1];   // [4,2048,128]
  const float* l2feat   = (const float*)d_in[2];   // [4,512,192]
  const float* l0_to_l1 = (const float*)d_in[3];   // [4,2048,8192]
  const float* l1_to_l2 = (const float*)d_in[4];   // [4,512,2048]
  const float* w21a = (const float*)d_in[5];
  const float* b21a = (const float*)d_in[6];
  const float* g21a = (const float*)d_in[7];
  const float* be21a = (const float*)d_in[8];
  const float* w21b = (const float*)d_in[9];
  const float* b21b = (const float*)d_in[10];
  const float* g21b = (const float*)d_in[11];
  const float* be21b = (const float*)d_in[12];
  const float* w10a = (const float*)d_in[13];
  const float* b10a = (const float*)d_in[14];
  const float* g10a = (const float*)d_in[15];
  const float* be10a = (const float*)d_in[16];
  const float* w10b = (const float*)d_in[17];
  const float* b10b = (const float*)d_in[18];
  const float* g10b = (const float*)d_in[19];
  const float* be10b = (const float*)d_in[20];

  u16* x1   = (u16*)d_ws;                       // [8192,320]
  u16* h1   = x1 + (size_t)8192 * 320;          // [8192,640]
  u16* fbuf = h1 + (size_t)8192 * 640;          // [8192,640]
  u16* xcat = fbuf + (size_t)8192 * 640;        // [32768,704]
  u16* h2   = xcat + (size_t)32768 * 704;       // [32768,640]
  u16* wb21a = h2 + (size_t)32768 * 640;        // [640,320]
  u16* wb21b = wb21a + 640 * 320;               // [640,640]
  u16* wb10a = wb21b + 640 * 640;               // [640,704]
  u16* wb10b = wb10a + 640 * 704;               // [768,640]
  // total ~117 MB of workspace

  cvt_kernel<<<(640 * 320 + 255) / 256, 256, 0, stream>>>(w21a, wb21a, 640 * 320);
  cvt_kernel<<<(640 * 640 + 255) / 256, 256, 0, stream>>>(w21b, wb21b, 640 * 640);
  cvt_kernel<<<(640 * 704 + 255) / 256, 256, 0, stream>>>(w10a, wb10a, 640 * 704);
  cvt_kernel<<<(768 * 640 + 255) / 256, 256, 0, stream>>>(w10b, wb10b, 768 * 640);

  knn_small_kernel<<<256, 512, 0, stream>>>(l1_to_l2, l2feat, l1feat, x1);
  gemm_bf16<0><<<5 * 64, 256, 0, stream>>>(wb21a, x1, b21a, g21a, be21a, h1, 640, 320, 8192);
  gemm_bf16<0><<<5 * 64, 256, 0, stream>>>(wb21b, h1, b21b, g21b, be21b, fbuf, 640, 640, 8192);
  knn_big_kernel<<<512, 1024, 0, stream>>>(l0_to_l1, fbuf, radar, xcat);
  gemm_bf16<0><<<5 * 256, 256, 0, stream>>>(wb10a, xcat, b10a, g10a, be10a, h2, 640, 704, 32768);
  gemm_bf16<1><<<6 * 256, 256, 0, stream>>>(wb10b, h2, b10b, g10b, be10b, d_out, 768, 640, 32768);
}

// Round 3
// 655.097 us; speedup vs baseline: 2.4475x; 1.0513x over previous
//
#include <hip/hip_runtime.h>
#include <stdint.h>

typedef unsigned short u16;
typedef __attribute__((ext_vector_type(8))) short short8;
typedef __attribute__((ext_vector_type(4))) short short4v;
typedef __attribute__((ext_vector_type(4))) float f32x4;
typedef __attribute__((ext_vector_type(4))) unsigned int u32x4;

__device__ __forceinline__ u16 f2bf(float f) {
  union { float f; uint32_t i; } v; v.f = f;
  uint32_t x = v.i;
  return (u16)((x + 0x7fffu + ((x >> 16) & 1u)) >> 16);  // RNE
}
__device__ __forceinline__ float bf2f(u16 u) {
  union { uint32_t i; float f; } v; v.i = ((uint32_t)u) << 16; return v.f;
}
__device__ __forceinline__ unsigned int packbf(float lo, float hi) {
  return (unsigned int)f2bf(lo) | ((unsigned int)f2bf(hi) << 16);
}

// async global -> LDS, 16B per lane. lds dest: wave-uniform base + lane*16 (HW adds lane offset).
__device__ __forceinline__ void gl_lds16(const void* g, void* l) {
  __builtin_amdgcn_global_load_lds(
      (const __attribute__((address_space(1))) void*)g,
      (__attribute__((address_space(3))) void*)l, 16, 0, 0);
}

// fp32 -> bf16 convert (weights)
__global__ __launch_bounds__(256) void cvt_kernel(const float* __restrict__ src,
                                                  u16* __restrict__ dst, int n) {
  int i = blockIdx.x * 256 + threadIdx.x;
  if (i < n) dst[i] = f2bf(src[i]);
}

// Branchless stable top-8-smallest insert.
// Sorted ascending td[0..7]. Insertion = td[j] <- med3(d, td[j-1], td[j]) (1 VALU/slot).
// Index tracking via strict-< compares (earlier stream index wins ties, matching top_k).
__device__ __forceinline__ void top8_insert(float (&td)[8], int (&ti)[8], float d, int idx) {
  bool c[8];
#pragma unroll
  for (int j = 0; j < 8; ++j) c[j] = d < td[j];
#pragma unroll
  for (int j = 7; j >= 1; --j) {
    ti[j] = c[j - 1] ? ti[j - 1] : (c[j] ? idx : ti[j]);
    td[j] = __builtin_amdgcn_fmed3f(d, td[j - 1], td[j]);
  }
  ti[0] = c[0] ? idx : ti[0];
  td[0] = fminf(td[0], d);
}

// merge two sorted 8-lists living in LDS (list i0 holds lower global indices than i1;
// <= keeps i0 on ties -> global stability)
__device__ __forceinline__ void merge2(const float (*sd)[9], const int (*si)[9],
                                       int i0, int i1, float (&md)[8], int (&mi)[8]) {
  int ia = 0, ib = 0;
#pragma unroll
  for (int r = 0; r < 8; ++r) {
    float da = sd[i0][ia], db = sd[i1][ib];
    bool ta = da <= db;
    md[r] = ta ? da : db;
    mi[r] = ta ? si[i0][ia] : si[i1][ib];
    if (ta) ++ia; else ++ib;
  }
}

// ---------------- KNN level2 -> level1 : x1 = concat(l1_cls_feat, interp192) as bf16 ----------------
// 256 blocks: each block = 32 columns (l1 points) of one batch.
// 512 threads = 16 row-segments x 32 columns; segment scans 32 of the 512 n2-rows.
__global__ __launch_bounds__(512) void knn_small_kernel(
    const float* __restrict__ l1_to_l2,  // [4,512,2048] fp32
    const float* __restrict__ l2feat,    // [4,512,192]  fp32
    const float* __restrict__ l1feat,    // [4,2048,128] fp32
    u16* __restrict__ x1)                // [4*2048, 320] bf16
{
  const int t = threadIdx.x;
  const int c = t & 31;                  // column within block
  const int seg = t >> 5;                // 0..15
  const int b = blockIdx.x >> 6;
  const int base = (blockIdx.x & 63) << 5;

  float td[8]; int ti[8];
#pragma unroll
  for (int j = 0; j < 8; ++j) { td[j] = 3.0e38f; ti[j] = 0; }

  const float* dpp = l1_to_l2 + (size_t)b * 512 * 2048 + (size_t)(seg * 32) * 2048 + base + c;
  int idx0 = seg * 32;
  for (int it = 0; it < 2; ++it) {       // 2 x 16 = 32 rows per segment
    float dv[16];
#pragma unroll
    for (int u = 0; u < 16; ++u) dv[u] = dpp[(size_t)u * 2048];
    dpp += (size_t)16 * 2048;
#pragma unroll
    for (int u = 0; u < 16; ++u) top8_insert(td, ti, dv[u], idx0 + u);
    idx0 += 16;
  }

  __shared__ float sd[512][9];
  __shared__ int   si[512][9];
  __shared__ float ws[32][8];
  __shared__ int   is_[32][8];
#pragma unroll
  for (int j = 0; j < 8; ++j) { sd[t][j] = td[j]; si[t][j] = ti[j]; }
  __syncthreads();

  float md[8]; int mi[8];
  // 16 -> 8
  if (t < 256) merge2(sd, si, t + ((t >> 5) << 5), t + ((t >> 5) << 5) + 32, md, mi);
  __syncthreads();
  if (t < 256) {
#pragma unroll
    for (int j = 0; j < 8; ++j) { sd[t][j] = md[j]; si[t][j] = mi[j]; }
  }
  __syncthreads();
  // 8 -> 4
  if (t < 128) merge2(sd, si, t + ((t >> 5) << 5), t + ((t >> 5) << 5) + 32, md, mi);
  __syncthreads();
  if (t < 128) {
#pragma unroll
    for (int j = 0; j < 8; ++j) { sd[t][j] = md[j]; si[t][j] = mi[j]; }
  }
  __syncthreads();
  // 4 -> 2
  if (t < 64) merge2(sd, si, t + ((t >> 5) << 5), t + ((t >> 5) << 5) + 32, md, mi);
  __syncthreads();
  if (t < 64) {
#pragma unroll
    for (int j = 0; j < 8; ++j) { sd[t][j] = md[j]; si[t][j] = mi[j]; }
  }
  __syncthreads();
  // 2 -> 1 + weights
  if (t < 32) {
    merge2(sd, si, t, t + 32, md, mi);
    float wv[8], s = 0.f;
#pragma unroll
    for (int j = 0; j < 8; ++j) { wv[j] = 1.f / (md[j] + 1e-8f); s += wv[j]; }
    const float inv = 1.f / (s + 1e-8f);
#pragma unroll
    for (int j = 0; j < 8; ++j) { ws[t][j] = wv[j] * inv; is_[t][j] = mi[j]; }
  }
  __syncthreads();

  // gather: 8 groups of 64 lanes; each group handles 4 of the 32 points
  const float* l2b = l2feat + (size_t)b * 512 * 192;
  const int g = t >> 6;                  // 0..7
  const int lane = t & 63;
  for (int p = 0; p < 4; ++p) {
    const int p2 = (g << 2) + p;
    float a0 = 0.f, a1 = 0.f, a2 = 0.f;
#pragma unroll
    for (int j = 0; j < 8; ++j) {
      const float wj = ws[p2][j];
      const float* frp = l2b + (size_t)is_[p2][j] * 192;
      a0 += wj * frp[lane];
      a1 += wj * frp[lane + 64];
      a2 += wj * frp[lane + 128];
    }
    const int row = b * 2048 + base + p2;
    u16* xr = x1 + (size_t)row * 320;
    const float* lf = l1feat + (size_t)row * 128;
    xr[lane]       = f2bf(lf[lane]);
    xr[64 + lane]  = f2bf(lf[64 + lane]);
    xr[128 + lane] = f2bf(a0);
    xr[192 + lane] = f2bf(a1);
    xr[256 + lane] = f2bf(a2);
  }
}

// ---------------- KNN level1 -> level0 : xcat = concat(radar64, interp640) as bf16 ----------------
// 1024 threads = 16 waves; wave w scans rows [w*128, w*128+128) of the 2048 n1-rows.
__global__ __launch_bounds__(1024) void knn_big_kernel(
    const float* __restrict__ dist,   // [4,2048,8192] fp32
    const u16* __restrict__ f,        // [4*2048,640] bf16
    const float* __restrict__ radar,  // [4,8192,64] fp32
    u16* __restrict__ xcat)           // [4*8192,704] bf16
{
  const int t = threadIdx.x;
  const int lane = t & 63;
  const int w = t >> 6;                  // 0..15
  const int b = blockIdx.x >> 7;
  const int base = (blockIdx.x & 127) << 6;

  float td[8]; int ti[8];
#pragma unroll
  for (int j = 0; j < 8; ++j) { td[j] = 3.0e38f; ti[j] = 0; }

  const float* dpp = dist + (size_t)b * 2048 * 8192 + (size_t)(w * 128) * 8192 + base + lane;
  int idx0 = w * 128;
  for (int it = 0; it < 8; ++it) {       // 8 x 16 = 128 rows per wave
    float dv[16];
#pragma unroll
    for (int u = 0; u < 16; ++u) dv[u] = dpp[(size_t)u * 8192];
    dpp += (size_t)16 * 8192;
#pragma unroll
    for (int u = 0; u < 16; ++u) top8_insert(td, ti, dv[u], idx0 + u);
    idx0 += 16;
  }

  __shared__ float sd[1024][9];
  __shared__ int   si[1024][9];
  __shared__ float ws[64][8];
  __shared__ int   is_[64][8];
#pragma unroll
  for (int j = 0; j < 8; ++j) { sd[t][j] = td[j]; si[t][j] = ti[j]; }
  __syncthreads();

  float md[8]; int mi[8];
  // 16 -> 8
  if (t < 512) merge2(sd, si, t + ((t >> 6) << 6), t + ((t >> 6) << 6) + 64, md, mi);
  __syncthreads();
  if (t < 512) {
#pragma unroll
    for (int j = 0; j < 8; ++j) { sd[t][j] = md[j]; si[t][j] = mi[j]; }
  }
  __syncthreads();
  // 8 -> 4
  if (t < 256) merge2(sd, si, t + ((t >> 6) << 6), t + ((t >> 6) << 6) + 64, md, mi);
  __syncthreads();
  if (t < 256) {
#pragma unroll
    for (int j = 0; j < 8; ++j) { sd[t][j] = md[j]; si[t][j] = mi[j]; }
  }
  __syncthreads();
  // 4 -> 2
  if (t < 128) merge2(sd, si, t + ((t >> 6) << 6), t + ((t >> 6) << 6) + 64, md, mi);
  __syncthreads();
  if (t < 128) {
#pragma unroll
    for (int j = 0; j < 8; ++j) { sd[t][j] = md[j]; si[t][j] = mi[j]; }
  }
  __syncthreads();
  // 2 -> 1 + weights
  if (t < 64) {
    merge2(sd, si, t, t + 64, md, mi);
    float wv[8], s = 0.f;
#pragma unroll
    for (int j = 0; j < 8; ++j) { wv[j] = 1.f / (md[j] + 1e-8f); s += wv[j]; }
    const float inv = 1.f / (s + 1e-8f);
#pragma unroll
    for (int j = 0; j < 8; ++j) { ws[t][j] = wv[j] * inv; is_[t][j] = mi[j]; }
  }
  __syncthreads();

  // gather: 8 groups of 128 threads; each group handles 8 points.
  // f rows (640 bf16 = 320 u32) read as u32 (2 bf16 per load, 256B/wave/instr).
  const u16* fb = f + (size_t)b * 2048 * 640;
  const int g = t >> 7;                  // 0..7
  const int t2 = t & 127;
  const bool lowhalf = (t2 < 64);        // wave-uniform
  for (int p = 0; p < 8; ++p) {
    const int p2 = (g << 3) + p;
    float a0l = 0.f, a0h = 0.f, a1l = 0.f, a1h = 0.f, a2l = 0.f, a2h = 0.f;
#pragma unroll
    for (int j = 0; j < 8; ++j) {
      const float wj = ws[p2][j];
      const unsigned int* fr32 = (const unsigned int*)(fb + (size_t)is_[p2][j] * 640);
      unsigned int v0 = fr32[t2];
      unsigned int v1 = fr32[t2 + 128];
      a0l += wj * bf2f((u16)(v0 & 0xffffu)); a0h += wj * bf2f((u16)(v0 >> 16));
      a1l += wj * bf2f((u16)(v1 & 0xffffu)); a1h += wj * bf2f((u16)(v1 >> 16));
      if (lowhalf) {
        unsigned int v2 = fr32[t2 + 256];
        a2l += wj * bf2f((u16)(v2 & 0xffffu)); a2h += wj * bf2f((u16)(v2 >> 16));
      }
    }
    const int row = (b << 13) + base + p2;
    u16* xr = xcat + (size_t)row * 704;
    if (lowhalf) xr[t2] = f2bf(radar[(size_t)row * 64 + t2]);
    unsigned int* xo = (unsigned int*)(xr + 64);
    xo[t2]       = packbf(a0l, a0h);
    xo[t2 + 128] = packbf(a1l, a1h);
    if (lowhalf) xo[t2 + 256] = packbf(a2l, a2h);
  }
}

// ---------------- fused GEMM + bias + BN(eval) + ReLU ----------------
// C[m,n] = relu(g[m]*inv_sqrt*(sum_k W[m,k]*X[n,k] + b[m]) + be[m])
// W:[M,K] bf16 k-fast, X:[Ntot,K] bf16 k-fast. bias/gamma/beta fp32.
// OUT_MODE 0: bf16 Y[n*M+m]; OUT_MODE 1: fp32 Y[b*M*8192+m*8192+(n%8192)]
// 2-phase double-buffered LDS pipeline: stage tile k+1 (global_load_lds) before
// compute of tile k; single __syncthreads (drains vmcnt) per K-step. K/BK always even.
#define BM 128
#define BN 128
#define BK 32

template <int OUT_MODE>
__global__ __launch_bounds__(256) void gemm_bf16(
    const u16* __restrict__ W, const u16* __restrict__ X,
    const float* __restrict__ bias, const float* __restrict__ gamma, const float* __restrict__ beta,
    void* __restrict__ Yv, int M, int K, int Ntot)
{
  __shared__ u16 As[2][BM * BK];
  __shared__ u16 Bs[2][BN * BK];

  const int t = threadIdx.x;
  const int lane = t & 63;
  const int wv = t >> 6;
  const int mtiles = M >> 7;
  const int mt = (int)blockIdx.x % mtiles;
  const int nt = (int)blockIdx.x / mtiles;
  const int m0 = mt << 7;
  const int n0 = nt << 7;
  const int fr = lane & 15;
  const int quad = lane >> 4;
  const int wr = (wv >> 1) << 6;  // wave m-offset within tile
  const int wc = (wv & 1) << 6;   // wave n-offset within tile

  const f32x4 zero = {0.f, 0.f, 0.f, 0.f};
  f32x4 acc[4][4];
#pragma unroll
  for (int i = 0; i < 4; ++i)
#pragma unroll
    for (int j = 0; j < 4; ++j) acc[i][j] = zero;

  // staging: 512 chunks of 16B per tile; chunk c -> row c/4, k8 (c%4)*8
  // chunk c0 = wv*64+lane -> LDS byte c0*16 : wave-uniform base + lane*16 (global_load_lds layout)
  const int c0 = (wv << 6) + lane;
  const int c1 = c0 + 256;
  const u16* Wp0 = W + (size_t)(m0 + (c0 >> 2)) * K + ((c0 & 3) << 3);
  const u16* Wp1 = W + (size_t)(m0 + (c1 >> 2)) * K + ((c1 & 3) << 3);
  const u16* Xp0 = X + (size_t)(n0 + (c0 >> 2)) * K + ((c0 & 3) << 3);
  const u16* Xp1 = X + (size_t)(n0 + (c1 >> 2)) * K + ((c1 & 3) << 3);

  auto stage = [&](int kk, int buf) {
    char* aB = (char*)As[buf];
    char* bB = (char*)Bs[buf];
    gl_lds16(Wp0 + kk, aB + ((size_t)c0 << 4));
    gl_lds16(Wp1 + kk, aB + ((size_t)c1 << 4));
    gl_lds16(Xp0 + kk, bB + ((size_t)c0 << 4));
    gl_lds16(Xp1 + kk, bB + ((size_t)c1 << 4));
  };
  auto compute = [&](int buf) {
    const u16* A = As[buf];
    const u16* B = Bs[buf];
    short8 af[4], bfv[4];
#pragma unroll
    for (int i = 0; i < 4; ++i)
      af[i] = *(const short8*)(A + (wr + i * 16 + fr) * BK + (quad << 3));
#pragma unroll
    for (int j = 0; j < 4; ++j)
      bfv[j] = *(const short8*)(B + (wc + j * 16 + fr) * BK + (quad << 3));
#pragma unroll
    for (int i = 0; i < 4; ++i)
#pragma unroll
      for (int j = 0; j < 4; ++j)
        acc[i][j] = __builtin_amdgcn_mfma_f32_16x16x32_bf16(af[i], bfv[j], acc[i][j], 0, 0, 0);
  };

  // prologue: stage tile 0 into buf 0
  stage(0, 0);
  __syncthreads();  // drains vmcnt(0) -> writes visible

  for (int k0 = 0; k0 < K; k0 += 2 * BK) {
    // phase A: compute buf0, prefetch k0+BK into buf1
    if (k0 + BK < K) stage(k0 + BK, 1);
    compute(0);
    __syncthreads();  // vmcnt drain + all waves done reading buf0
    // phase B: compute buf1, prefetch k0+2BK into buf0
    if (k0 + 2 * BK < K) stage(k0 + 2 * BK, 0);
    compute(1);
    __syncthreads();
  }

  // epilogue: C/D layout col=lane&15 (n), row=quad*4+r (m)
  constexpr float BNS = 0.99999500003749968f;  // 1/sqrt(1+1e-5)
#pragma unroll
  for (int i = 0; i < 4; ++i) {
    const int mb = m0 + wr + i * 16 + (quad << 2);
    float g0[4], b0[4], e0[4];
#pragma unroll
    for (int r = 0; r < 4; ++r) {
      g0[r] = gamma[mb + r] * BNS;
      b0[r] = bias[mb + r];
      e0[r] = beta[mb + r];
    }
#pragma unroll
    for (int j = 0; j < 4; ++j) {
      const int n = n0 + wc + j * 16 + fr;
      if (OUT_MODE == 0) {
        u16* Y = (u16*)Yv;
        short4v sv;
#pragma unroll
        for (int r = 0; r < 4; ++r) {
          float v = g0[r] * (acc[i][j][r] + b0[r]) + e0[r];
          sv[r] = (short)f2bf(fmaxf(v, 0.f));
        }
        *(short4v*)(Y + (size_t)n * M + mb) = sv;
      } else {
        float* Y = (float*)Yv;
        const int bb = n >> 13, nn = n & 8191;
        float* yp = Y + ((size_t)bb * M + mb) * 8192 + nn;
#pragma unroll
        for (int r = 0; r < 4; ++r) {
          float v = g0[r] * (acc[i][j][r] + b0[r]) + e0[r];
          yp[(size_t)r * 8192] = fmaxf(v, 0.f);
        }
      }
    }
  }
}

extern "C" void kernel_launch(void* const* d_in, const int* in_sizes, int n_in,
                              void* d_out, int out_size, void* d_ws, size_t ws_size,
                              hipStream_t stream) {
  (void)in_sizes; (void)n_in; (void)out_size; (void)ws_size;
  const float* radar    = (const float*)d_in[0];   // [4,8192,64]
  const float* l1feat   = (const float*)d_in[1];   // [4,2048,128]
  const float* l2feat   = (const float*)d_in[2];   // [4,512,192]
  const float* l0_to_l1 = (const float*)d_in[3];   // [4,2048,8192]
  const float* l1_to_l2 = (const float*)d_in[4];   // [4,512,2048]
  const float* w21a = (const float*)d_in[5];
  const float* b21a = (const float*)d_in[6];
  const float* g21a = (const float*)d_in[7];
  const float* be21a = (const float*)d_in[8];
  const float* w21b = (const float*)d_in[9];
  const float* b21b = (const float*)d_in[10];
  const float* g21b = (const float*)d_in[11];
  const float* be21b = (const float*)d_in[12];
  const float* w10a = (const float*)d_in[13];
  const float* b10a = (const float*)d_in[14];
  const float* g10a = (const float*)d_in[15];
  const float* be10a = (const float*)d_in[16];
  const float* w10b = (const float*)d_in[17];
  const float* b10b = (const float*)d_in[18];
  const float* g10b = (const float*)d_in[19];
  const float* be10b = (const float*)d_in[20];

  u16* x1   = (u16*)d_ws;                       // [8192,320]
  u16* h1   = x1 + (size_t)8192 * 320;          // [8192,640]
  u16* fbuf = h1 + (size_t)8192 * 640;          // [8192,640]
  u16* xcat = fbuf + (size_t)8192 * 640;        // [32768,704]
  u16* h2   = xcat + (size_t)32768 * 704;       // [32768,640]
  u16* wb21a = h2 + (size_t)32768 * 640;        // [640,320]
  u16* wb21b = wb21a + 640 * 320;               // [640,640]
  u16* wb10a = wb21b + 640 * 640;               // [640,704]
  u16* wb10b = wb10a + 640 * 704;               // [768,640]
  // total ~117 MB of workspace

  cvt_kernel<<<(640 * 320 + 255) / 256, 256, 0, stream>>>(w21a, wb21a, 640 * 320);
  cvt_kernel<<<(640 * 640 + 255) / 256, 256, 0, stream>>>(w21b, wb21b, 640 * 640);
  cvt_kernel<<<(640 * 704 + 255) / 256, 256, 0, stream>>>(w10a, wb10a, 640 * 704);
  cvt_kernel<<<(768 * 640 + 255) / 256, 256, 0, stream>>>(w10b, wb10b, 768 * 640);

  knn_small_kernel<<<256, 512, 0, stream>>>(l1_to_l2, l2feat, l1feat, x1);
  gemm_bf16<0><<<5 * 64, 256, 0, stream>>>(wb21a, x1, b21a, g21a, be21a, h1, 640, 320, 8192);
  gemm_bf16<0><<<5 * 64, 256, 0, stream>>>(wb21b, h1, b21b, g21b, be21b, fbuf, 640, 640, 8192);
  knn_big_kernel<<<512, 1024, 0, stream>>>(l0_to_l1, fbuf, radar, xcat);
  gemm_bf16<0><<<5 * 256, 256, 0, stream>>>(wb10a, xcat, b10a, g10a, be10a, h2, 640, 704, 32768);
  gemm_bf16<1><<<6 * 256, 256, 0, stream>>>(wb10b, h2, b10b, g10b, be10b, d_out, 768, 640, 32768);
}